// Round 7
// baseline (272.100 us; speedup 1.0000x reference)
//
#include <hip/hip_runtime.h>
#include <stdint.h>

// PenalizedMSELoss: out = mean(w * (x - t)^2), w = 3.0 if (4.5 < x < 5.5 && t != 5) else 1.0
// x: float32[N], t: int32[N], out: float32[1]. 268 MB single-use read.
// R1: 105us MLP~2. R3: 99us MLP~4. R4: asm-pin MLP=8 -> ~75us. R5: MLP=16 FLAT
//   => ~5.9 B/cyc/CU cap on the VGPR-return read path. Fill kernel: 6.9 TB/s.
// R6: LDS-DMA attempt FAILED correctness — used lds_ptr+off AND offset field
//   together (semantics ambiguous) + manual vmcnt(8) partial wait.
// R7: LDS-DMA, de-risked: offset=0 everywhere (explicit pointers only),
//   conservative vmcnt(0)+lgkmcnt(0) drain, C-level consume, no syncthreads.

#define LABEL_I   5
#define LOWER_F   4.5f
#define UPPER_F   5.5f
#define PENALTY_F 3.0f

typedef float vf4 __attribute__((ext_vector_type(4)));
typedef int   vi4 __attribute__((ext_vector_type(4)));

typedef __attribute__((address_space(1))) const void g_void;
typedef __attribute__((address_space(3))) void       l_void;
typedef __attribute__((address_space(3))) char       l_char;

__device__ __forceinline__ float term(float x, int t) {
    float d = x - (float)t;
    float w = (x > LOWER_F && x < UPPER_F && t != LABEL_I) ? PENALTY_F : 1.0f;
    return w * d * d;
}

__device__ __forceinline__ float term4(vf4 xv, vi4 tv) {
    return term(xv.x, tv.x) + term(xv.y, tv.y) + term(xv.z, tv.z) + term(xv.w, tv.w);
}

// Tile per block-iteration: 1024 vf4 from each array (16 KB x + 16 KB t).
// Per wave: 256 vf4 (4 KB) per array per buffer.
#define TILE_V4 1024

// Stage one wave-private buffer. Each global_load_lds: 64 lanes x 16 B = 1 KB,
// LDS dest = wave-uniform base + lane*16 (HW). offset field = 0 ALWAYS; all
// addressing is explicit in the pointers (R6 failure suspect #1).
#define STAGE(buf, tileIdx) do {                                               \
    int gb = (tileIdx) * TILE_V4 + wave * 256 + lane;                          \
    const vf4* xp = x4 + gb;                                                   \
    const vi4* tp = t4 + gb;                                                   \
    l_char* lx = (l_char*)&ldsx[buf][wave][0];                                 \
    l_char* lt = (l_char*)&ldst[buf][wave][0];                                 \
    __builtin_amdgcn_global_load_lds((g_void*)(const void*)(xp),       (l_void*)(lx),        16, 0, 0); \
    __builtin_amdgcn_global_load_lds((g_void*)(const void*)(tp),       (l_void*)(lt),        16, 0, 0); \
    __builtin_amdgcn_global_load_lds((g_void*)(const void*)(xp + 64),  (l_void*)(lx + 1024), 16, 0, 0); \
    __builtin_amdgcn_global_load_lds((g_void*)(const void*)(tp + 64),  (l_void*)(lt + 1024), 16, 0, 0); \
    __builtin_amdgcn_global_load_lds((g_void*)(const void*)(xp + 128), (l_void*)(lx + 2048), 16, 0, 0); \
    __builtin_amdgcn_global_load_lds((g_void*)(const void*)(tp + 128), (l_void*)(lt + 2048), 16, 0, 0); \
    __builtin_amdgcn_global_load_lds((g_void*)(const void*)(xp + 192), (l_void*)(lx + 3072), 16, 0, 0); \
    __builtin_amdgcn_global_load_lds((g_void*)(const void*)(tp + 192), (l_void*)(lt + 3072), 16, 0, 0); \
} while (0)

// Conservative drain (covers DMA under either counter), then plain C consume:
// lane reads its own 4 vf4 per array (ds_read_b128, compiler-managed waits).
#define CONSUME(buf) do {                                                      \
    asm volatile("s_waitcnt vmcnt(0) lgkmcnt(0)" ::: "memory");                \
    const vf4* lxv = (const vf4*)&ldsx[buf][wave][0];                          \
    const vi4* ltv = (const vi4*)&ldst[buf][wave][0];                          \
    vf4 X0 = lxv[lane];       vi4 T0 = ltv[lane];                              \
    vf4 X1 = lxv[lane + 64];  vi4 T1 = ltv[lane + 64];                         \
    vf4 X2 = lxv[lane + 128]; vi4 T2 = ltv[lane + 128];                        \
    vf4 X3 = lxv[lane + 192]; vi4 T3 = ltv[lane + 192];                        \
    s0 += term4(X0, T0); s1 += term4(X1, T1);                                  \
    s2 += term4(X2, T2); s3 += term4(X3, T3);                                  \
} while (0)

__global__ __launch_bounds__(256) void penal_mse_stage1(
        const vf4* __restrict__ x4,
        const vi4* __restrict__ t4,
        float* __restrict__ partials,
        int n4, int tiles_total, int n_tail_start, int n_total,
        const float* __restrict__ x_scalar,
        const int*  __restrict__ t_scalar) {
    // Per-wave private double buffers: [buf][wave][256 vf4] = 4 KB each.
    __shared__ vf4 ldsx[2][4][256];   // 32 KB
    __shared__ vi4 ldst[2][4][256];   // 32 KB  (64 KB total -> 2 blocks/CU)

    const int wave = threadIdx.x >> 6;
    const int lane = threadIdx.x & 63;

    float s0 = 0.0f, s1 = 0.0f, s2 = 0.0f, s3 = 0.0f;

    int ntiles = 0;
    if ((int)blockIdx.x < tiles_total)
        ntiles = (tiles_total - 1 - (int)blockIdx.x) / (int)gridDim.x + 1;

    if (ntiles > 0) {
        STAGE(0, (int)blockIdx.x);
        int tile = (int)blockIdx.x;
        for (int i = 0; i < ntiles; ++i) {
            int buf = i & 1;
            if (i + 1 < ntiles)
                STAGE(buf ^ 1, tile + (int)gridDim.x);  // prefetch before drain
            CONSUME(buf);
            tile += (int)gridDim.x;
        }
    }

    // Leftover vf4 groups beyond full tiles (empty for N = 2^25).
    for (int i = tiles_total * TILE_V4 + (int)(blockIdx.x * blockDim.x + threadIdx.x);
         i < n4; i += (int)(gridDim.x * blockDim.x))
        s0 += term4(x4[i], t4[i]);

    // Scalar tail (N % 4 != 0) — empty for N = 2^25.
    for (int j = n_tail_start + (int)(blockIdx.x * blockDim.x + threadIdx.x);
         j < n_total; j += (int)(gridDim.x * blockDim.x))
        s0 += term(x_scalar[j], t_scalar[j]);

    float sum = (s0 + s1) + (s2 + s3);

    // Wave-64 shuffle reduction, then per-block partial to workspace.
    #pragma unroll
    for (int off = 32; off > 0; off >>= 1)
        sum += __shfl_down(sum, off, 64);

    __shared__ float wsum[4];
    if (lane == 0) wsum[wave] = sum;
    __syncthreads();

    if (threadIdx.x == 0)
        partials[blockIdx.x] = (wsum[0] + wsum[1]) + (wsum[2] + wsum[3]);
}

__global__ __launch_bounds__(256) void penal_mse_stage2(
        const float* __restrict__ partials, int nparts,
        float* __restrict__ out, float inv_n) {
    float sum = 0.0f;
    for (int i = threadIdx.x; i < nparts; i += 256)
        sum += partials[i];

    #pragma unroll
    for (int off = 32; off > 0; off >>= 1)
        sum += __shfl_down(sum, off, 64);

    __shared__ float wsum[4];
    int lane = threadIdx.x & 63;
    int wave = threadIdx.x >> 6;
    if (lane == 0) wsum[wave] = sum;
    __syncthreads();

    if (threadIdx.x == 0)
        out[0] = ((wsum[0] + wsum[1]) + (wsum[2] + wsum[3])) * inv_n;
}

extern "C" void kernel_launch(void* const* d_in, const int* in_sizes, int n_in,
                              void* d_out, int out_size, void* d_ws, size_t ws_size,
                              hipStream_t stream) {
    const float* x = (const float*)d_in[0];
    const int*   t = (const int*)d_in[1];
    float* out = (float*)d_out;
    float* partials = (float*)d_ws;

    int n  = in_sizes[0];
    int n4 = n >> 2;                  // vf4 groups
    int n_tail_start = n4 << 2;
    int tiles_total = n4 / TILE_V4;   // 8192 at N = 2^25
    float inv_n = 1.0f / (float)n;

    const int block = 256;
    const int grid = 512;             // 2 blocks/CU (64 KB LDS each), 16 tiles/block

    penal_mse_stage1<<<grid, block, 0, stream>>>(
        (const vf4*)x, (const vi4*)t, partials,
        n4, tiles_total, n_tail_start, n, x, t);

    penal_mse_stage2<<<1, block, 0, stream>>>(partials, grid, out, inv_n);
}